// Round 18
// baseline (5606.459 us; speedup 1.0000x reference)
//
#include <hip/hip_runtime.h>
#include <hip/hip_bf16.h>

typedef __attribute__((ext_vector_type(8))) _Float16 half8;
typedef __attribute__((ext_vector_type(4))) float f32x4;
typedef __attribute__((ext_vector_type(4))) unsigned int uint4v;

#define MFMA_F16(a,b,c) __builtin_amdgcn_mfma_f32_16x16x32_f16((a),(b),(c),0,0,0)

namespace {
constexpr int kNS = 256, kNA = 8, kNI = 256, kNH = 512;
constexpr size_t kOutElems = (size_t)64*kNS*kNA*kNH;  // 33,554,432
constexpr float kScale = 2048.0f;
constexpr float kInv   = 1.0f/2048.0f;
constexpr int kWihHi = 0;
constexpr int kWihLo = 24576;
constexpr int kWhhHi = 49152;
constexpr int kWhhLo = 98304;
constexpr int kSmem  = 147456;     // 147 KB dynamic -> 1 wg/CU
constexpr size_t kHPhase = 262144; // u32 elements per phase (512x512)
}

// h exchange: packed u32 (fp16 hi | lo<<16). Layout: (mi*4+w)*8192 + kb*512 +
// l*8 + e  -> lane l reads TWO dwordx4 per kb (contiguous 2 KB per wave/kb).
// Fast path: plain L2 write-back stores + sc0 (L1-bypass) loads — the 32 wgs
// of a group share one XCD's coherent L2 (verified at runtime via XCC_ID;
// falls back to L3 path (sc0 sc1) if the mapping doesn't hold). R17's agent
// atomics bypassed L2 entirely (sc0+sc1) -> 1.58 GB TCC writes, 32x-redundant
// L3 reads on the critical path.
__device__ unsigned int g_hpk[2*kHPhase];   // 2 MB
__device__ unsigned int g_flag[4096];       // 256 wgs x 16-dword stride
__device__ int          g_mode;             // is_init dtype

__device__ __forceinline__ float sigmoid_f(float v) { return 1.0f/(1.0f + __expf(-v)); }
__device__ __forceinline__ float tanh_f(float v) {
    float e = __expf(2.0f*v);
    return 1.0f - 2.0f/(e + 1.0f);
}
__device__ __forceinline__ void split2(float v, unsigned short& hi, unsigned short& lo) {
    _Float16 h = (_Float16)v;
    _Float16 l = (_Float16)((v - (float)h) * kScale);
    hi = __builtin_bit_cast(unsigned short, h);
    lo = __builtin_bit_cast(unsigned short, l);
}
__device__ __forceinline__ uint4v ld128_sc0(const unsigned int* p) {
    uint4v r;
    asm volatile("global_load_dwordx4 %0, %1, off sc0" : "=v"(r) : "v"(p));
    return r;
}
__device__ __forceinline__ uint4v ld128_sc01(const unsigned int* p) {
    uint4v r;
    asm volatile("global_load_dwordx4 %0, %1, off sc0 sc1" : "=v"(r) : "v"(p));
    return r;
}
#define WAITV(n) do { asm volatile("s_waitcnt vmcnt(" #n ")" ::: "memory"); \
                      __builtin_amdgcn_sched_barrier(0); } while(0)

__global__ void gru_prep(const unsigned int* __restrict__ is_init_raw) {
    for (int i = threadIdx.x; i < 4096; i += 256)
        __hip_atomic_store(&g_flag[i], 0u, __ATOMIC_RELAXED, __HIP_MEMORY_SCOPE_AGENT);
    if (threadIdx.x == 0) g_mode = 0;
    __syncthreads();
    unsigned m = 0;
    for (int i = threadIdx.x; i < 4096; i += 256) {
        unsigned v = is_init_raw[i];
        if (v == 0x00003F80u || v == 0x3F803F80u) m |= 4u;
        else if (v == 0x3F800000u)                m |= 2u;
        else if (v > 1u)                          m |= 1u;
    }
    if (m) atomicOr(&g_mode, (int)m);
}

// Persistent GRU. 256 wgs x 256 thr; 1 wg/CU. mi = bx&7 (8 groups x 64 rows,
// 32 wgs/group), ci = bx>>3 (32 col-blocks x 16). Split-fp16 MFMA, fp32 h.
__global__ void __launch_bounds__(256, 1)
gru_main(const float* __restrict__ x, const void* __restrict__ is_init,
         const float* __restrict__ w_ih, const float* __restrict__ w_hh,
         const float* __restrict__ b_ih, const float* __restrict__ b_hh,
         float* __restrict__ out)
{
    extern __shared__ char smem[];
    __shared__ int s_l3;
    const int tid = threadIdx.x;
    const int bx  = blockIdx.x;
    const int mi  = bx & 7;
    const int ci  = bx >> 3;
    const int c0  = ci * 16;

    for (int idx = tid; idx < 3072; idx += 256) {           // w_ih: 48 x 64 float4
        int jr = idx >> 6, q = idx & 63;
        int j = (jr >> 4)*kNH + c0 + (jr & 15);
        float4 v = *(const float4*)(w_ih + (size_t)j*kNI + q*4);
        ushort4 hi, lo;
        split2(v.x, hi.x, lo.x); split2(v.y, hi.y, lo.y);
        split2(v.z, hi.z, lo.z); split2(v.w, hi.w, lo.w);
        unsigned off = ((unsigned)(jr*512 + q*8)) ^ ((unsigned)(jr & 7) << 4);
        *(ushort4*)(smem + kWihHi + off) = hi;
        *(ushort4*)(smem + kWihLo + off) = lo;
    }
    for (int idx = tid; idx < 6144; idx += 256) {           // w_hh: 48 x 128 float4
        int jr = idx >> 7, q = idx & 127;
        int j = (jr >> 4)*kNH + c0 + (jr & 15);
        float4 v = *(const float4*)(w_hh + (size_t)j*kNH + q*4);
        ushort4 hi, lo;
        split2(v.x, hi.x, lo.x); split2(v.y, hi.y, lo.y);
        split2(v.z, hi.z, lo.z); split2(v.w, hi.w, lo.w);
        unsigned off = ((unsigned)(jr*1024 + q*8)) ^ ((unsigned)(jr & 7) << 4);
        *(ushort4*)(smem + kWhhHi + off) = hi;
        *(ushort4*)(smem + kWhhLo + off) = lo;
    }
    __syncthreads();

    const int fm = g_mode;
    const int fmode = (fm & 4) ? 3 : (fm & 2) ? 2 : (fm & 1) ? 1 : 0;

    const int l    = tid & 63, w = tid >> 6;
    const int lrow = l & 15, kgrp = l >> 4;

    const int cE = c0 + lrow;
    const int mA = mi*64 + w*16 + lrow;
    const int bA = mA >> 3;
    const size_t xrow0 = ((size_t)bA*(kNS*kNA) + (mA & 7))*kNI + kgrp*8;

    const unsigned swzb = (unsigned)(lrow & 7) << 4;
    unsigned wihB[3], whhB[3];
    #pragma unroll
    for (int g = 0; g < 3; ++g) {
        wihB[g] = (unsigned)((g*16 + lrow)*512  + kgrp*16);
        whhB[g] = (unsigned)((g*16 + lrow)*1024 + kgrp*16);
    }

    const float biasR  = b_ih[cE]        + b_hh[cE];
    const float biasZ  = b_ih[kNH + cE]  + b_hh[kNH + cE];
    const float biasIN = b_ih[2*kNH + cE];
    const float biasHN = b_hh[2*kNH + cE];
    const int mE0 = mi*64 + w*16 + kgrp*4;
    const int bE  = mE0 >> 3, aE0 = mE0 & 7;

    float hreg[4] = {0.f, 0.f, 0.f, 0.f};
    float* hn_out = out + kOutElems;
    int dead = 0;
    const unsigned myFlag  = (unsigned)((mi*32 + ci)*16);
    const unsigned grpFlag = (unsigned)(mi*32)*16;

    // Exchange addressing (lane-contiguous layout)
    const unsigned hRdBase = (unsigned)((mi*4 + w)*8192);   // + kb*512 + l*8 (+0/+4)
    const unsigned hWrBase = (unsigned)((mi*4 + w)*8192
                              + ((cE >> 5) * 512)
                              + ((((cE >> 3) & 3)*16 + kgrp*4) * 8)
                              + (cE & 7));                  // + i*8

    // ---- XCD-coherence probe: all 32 wgs of this group on one XCD? ----
    unsigned myXcc;
    asm volatile("s_getreg_b32 %0, hwreg(HW_REG_XCC_ID)" : "=s"(myXcc));
    if (tid == 0) {
        s_l3 = 0;
        __hip_atomic_store(&g_flag[myFlag + 1], myXcc + 1u,
                           __ATOMIC_RELAXED, __HIP_MEMORY_SCOPE_AGENT);
    }
    __syncthreads();
    if (tid < 32) {
        long it = 0; unsigned v;
        while ((v = __hip_atomic_load(&g_flag[grpFlag + tid*16 + 1], __ATOMIC_RELAXED,
                                      __HIP_MEMORY_SCOPE_AGENT)) == 0u) {
            if (++it > 50000000L) { v = 0xFFFFu; break; }
            __builtin_amdgcn_s_sleep(1);
        }
        if (v != myXcc + 1u) atomicOr(&s_l3, 1);
    }
    __syncthreads();
    const bool l3 = (s_l3 != 0);   // true -> L3 fallback (mapping not XCD-local)

#define LOADX(dh, dl, ss) do {                                                     \
        const float* xr_ = x + xrow0 + (size_t)(ss)*(kNA*kNI);                     \
        _Pragma("unroll")                                                          \
        for (int kb_ = 0; kb_ < 8; ++kb_) {                                        \
            float4 v0_ = *(const float4*)(xr_ + kb_*32);                           \
            float4 v1_ = *(const float4*)(xr_ + kb_*32 + 4);                       \
            float vv_[8] = {v0_.x,v0_.y,v0_.z,v0_.w,v1_.x,v1_.y,v1_.z,v1_.w};      \
            half8 th_, tl_;                                                        \
            _Pragma("unroll")                                                      \
            for (int e_ = 0; e_ < 8; ++e_) {                                       \
                _Float16 h_ = (_Float16)vv_[e_];                                   \
                th_[e_] = h_;                                                      \
                tl_[e_] = (_Float16)((vv_[e_] - (float)h_) * kScale);              \
            }                                                                      \
            dh[kb_] = th_; dl[kb_] = tl_;                                          \
        }                                                                          \
    } while (0)

#define ISSUEQ(dst, kb0) do {                                                      \
        if (l3) { _Pragma("unroll")                                                \
            for (int kk_ = 0; kk_ < 4; ++kk_) {                                    \
                const unsigned int* p_ = hpb + (kb0 + kk_)*512 + l*8;              \
                dst[2*kk_]   = ld128_sc01(p_);                                     \
                dst[2*kk_+1] = ld128_sc01(p_ + 4);                                 \
            }                                                                      \
        } else { _Pragma("unroll")                                                 \
            for (int kk_ = 0; kk_ < 4; ++kk_) {                                    \
                const unsigned int* p_ = hpb + (kb0 + kk_)*512 + l*8;              \
                dst[2*kk_]   = ld128_sc0(p_);                                      \
                dst[2*kk_+1] = ld128_sc0(p_ + 4);                                  \
            }                                                                      \
        }                                                                          \
    } while (0)

#define PROCQ(arr, kb0) do {                                                       \
        _Pragma("unroll")                                                          \
        for (int kk_ = 0; kk_ < 4; ++kk_) {                                        \
            const int kb = kb0 + kk_;                                              \
            uint4v q0 = arr[2*kk_], q1 = arr[2*kk_+1];                             \
            uint4v ph, pl;                                                         \
            ph[0]=(q0[0]&0xFFFFu)|(q0[1]<<16); pl[0]=(q0[0]>>16)|(q0[1]&0xFFFF0000u); \
            ph[1]=(q0[2]&0xFFFFu)|(q0[3]<<16); pl[1]=(q0[2]>>16)|(q0[3]&0xFFFF0000u); \
            ph[2]=(q1[0]&0xFFFFu)|(q1[1]<<16); pl[2]=(q1[0]>>16)|(q1[1]&0xFFFF0000u); \
            ph[3]=(q1[2]&0xFFFFu)|(q1[3]<<16); pl[3]=(q1[2]>>16)|(q1[3]&0xFFFF0000u); \
            half8 ahi = __builtin_bit_cast(half8, ph);                             \
            half8 alo = __builtin_bit_cast(half8, pl);                             \
            const half8 zz_ = {};                                                  \
            ahi = iniA ? zz_ : ahi;                                                \
            alo = iniA ? zz_ : alo;                                                \
            {   half8 bhi = *(const half8*)(smem + kWhhHi + ((whhB[0] + kb*64) ^ swzb)); \
                half8 blo = *(const half8*)(smem + kWhhLo + ((whhB[0] + kb*64) ^ swzb)); \
                aR = MFMA_F16(ahi, bhi, aR);                                       \
                lR = MFMA_F16(alo, bhi, lR);                                       \
                lR = MFMA_F16(ahi, blo, lR); }                                     \
            {   half8 bhi = *(const half8*)(smem + kWhhHi + ((whhB[1] + kb*64) ^ swzb)); \
                half8 blo = *(const half8*)(smem + kWhhLo + ((whhB[1] + kb*64) ^ swzb)); \
                aZ = MFMA_F16(ahi, bhi, aZ);                                       \
                lZ = MFMA_F16(alo, bhi, lZ);                                       \
                lZ = MFMA_F16(ahi, blo, lZ); }                                     \
            {   half8 bhi = *(const half8*)(smem + kWhhHi + ((whhB[2] + kb*64) ^ swzb)); \
                half8 blo = *(const half8*)(smem + kWhhLo + ((whhB[2] + kb*64) ^ swzb)); \
                aHN = MFMA_F16(ahi, bhi, aHN);                                     \
                lHN = MFMA_F16(alo, bhi, lHN);                                     \
                lHN = MFMA_F16(ahi, blo, lHN); }                                   \
        }                                                                          \
    } while (0)

    half8 xfh[8], xfl[8], xnh[8], xnl[8];
    LOADX(xfh, xfl, 0);

    for (int s = 0; s < kNS; ++s) {
        const int ii = bA*kNS + s;
        const int ie = bE*kNS + s;
        int iniA, iniE;
        switch (fmode) {
            case 3:  iniA = ((const unsigned short*)is_init)[ii] != 0;
                     iniE = ((const unsigned short*)is_init)[ie] != 0; break;
            case 2:  iniA = ((const float*)is_init)[ii] != 0.f;
                     iniE = ((const float*)is_init)[ie] != 0.f;       break;
            case 1:  iniA = ((const unsigned char*)is_init)[ii] != 0;
                     iniE = ((const unsigned char*)is_init)[ie] != 0; break;
            default: iniA = ((const int*)is_init)[ii] != 0;
                     iniE = ((const int*)is_init)[ie] != 0;           break;
        }
        f32x4 aR = {0,0,0,0}, aZ = {0,0,0,0}, aGN = {0,0,0,0}, aHN = {0,0,0,0};
        f32x4 lR = {0,0,0,0}, lZ = {0,0,0,0}, lGN = {0,0,0,0}, lHN = {0,0,0,0};

        // ---- gi (independent of h) ----
        #pragma unroll
        for (int kb = 0; kb < 8; ++kb) {
            {   half8 bhi = *(const half8*)(smem + kWihHi + ((wihB[0] + kb*64) ^ swzb));
                half8 blo = *(const half8*)(smem + kWihLo + ((wihB[0] + kb*64) ^ swzb));
                aR = MFMA_F16(xfh[kb], bhi, aR);
                lR = MFMA_F16(xfl[kb], bhi, lR);
                lR = MFMA_F16(xfh[kb], blo, lR); }
            {   half8 bhi = *(const half8*)(smem + kWihHi + ((wihB[1] + kb*64) ^ swzb));
                half8 blo = *(const half8*)(smem + kWihLo + ((wihB[1] + kb*64) ^ swzb));
                aZ = MFMA_F16(xfh[kb], bhi, aZ);
                lZ = MFMA_F16(xfl[kb], bhi, lZ);
                lZ = MFMA_F16(xfh[kb], blo, lZ); }
            {   half8 bhi = *(const half8*)(smem + kWihHi + ((wihB[2] + kb*64) ^ swzb));
                half8 blo = *(const half8*)(smem + kWihLo + ((wihB[2] + kb*64) ^ swzb));
                aGN = MFMA_F16(xfh[kb], bhi, aGN);
                lGN = MFMA_F16(xfl[kb], bhi, lGN);
                lGN = MFMA_F16(xfh[kb], blo, lGN); }
        }

        if (s + 1 < kNS) LOADX(xnh, xnl, s + 1);

        // ---- wait for h(s), then pipelined gh ----
        if (s > 0) {
            if (tid < 32 && !dead) {
                const unsigned target = (unsigned)s;
                long it = 0;
                while (__hip_atomic_load(&g_flag[grpFlag + tid*16], __ATOMIC_RELAXED,
                                         __HIP_MEMORY_SCOPE_AGENT) < target) {
                    if (++it > 50000000L) { dead = 1; break; }
                    __builtin_amdgcn_s_sleep(1);
                }
            }
            __syncthreads();
            const unsigned int* hpb = g_hpk + (size_t)(s & 1)*kHPhase + hRdBase;
            uint4v hA[8], hB[8];
            ISSUEQ(hA, 0);
            ISSUEQ(hB, 4);
            WAITV(8);          // hA ready (x-prefetch drains too; it's older)
            PROCQ(hA, 0);
            ISSUEQ(hA, 8);
            WAITV(8);          // hB ready
            PROCQ(hB, 4);
            ISSUEQ(hB, 12);
            WAITV(8);          // hA(8..11) ready
            PROCQ(hA, 8);
            WAITV(0);          // hB(12..15) ready
            PROCQ(hB, 12);
        }

        // ---- gates + h update; h stores first (critical path) ----
        unsigned int* hw = g_hpk + (size_t)((s+1) & 1)*kHPhase + hWrBase;
        float hvout[4];
        #pragma unroll
        for (int i = 0; i < 4; ++i) {
            float pr  = aR[i]  + lR[i]*kInv  + biasR;
            float pz  = aZ[i]  + lZ[i]*kInv  + biasZ;
            float gin = aGN[i] + lGN[i]*kInv + biasIN;
            float ghn = aHN[i] + lHN[i]*kInv + biasHN;
            float htv = iniE ? 0.f : hreg[i];
            float r  = sigmoid_f(pr);
            float zg = sigmoid_f(pz);
            float nn = tanh_f(gin + r*ghn);
            float hv = (1.f - zg)*nn + zg*htv;
            hreg[i] = hv; hvout[i] = hv;
            unsigned short shi, slo;
            split2(hv, shi, slo);
            unsigned int pk = (unsigned)shi | ((unsigned)slo << 16);
            if (l3)
                asm volatile("global_store_dword %0, %1, off sc0 sc1"
                             :: "v"(hw + i*8), "v"(pk) : "memory");
            else
                hw[i*8] = pk;        // plain L2 write-back (XCD-local)
        }

        // ---- publish h(s+1): drain ALL stores (incl. asm), then flag ----
        if (s < kNS-1) {
            asm volatile("s_waitcnt vmcnt(0)" ::: "memory");
            __syncthreads();
            if (tid == 0)
                __hip_atomic_store(&g_flag[myFlag], (unsigned)(s+1),
                                   __ATOMIC_RELAXED, __HIP_MEMORY_SCOPE_AGENT);
        }

        // ---- out stores off the critical path ----
        const size_t obase = ((size_t)bE*(kNS*kNA) + (size_t)s*kNA + aE0)*kNH + cE;
        #pragma unroll
        for (int i = 0; i < 4; ++i)
            out[obase + (size_t)i*kNH] = hvout[i];
        if (s == kNS-1) {
            #pragma unroll
            for (int i = 0; i < 4; ++i)
                hn_out[(size_t)(mE0 + i)*kNH + cE] = hreg[i];
        }

        if (s < kNS-1) {
            #pragma unroll
            for (int i = 0; i < 8; ++i) { xfh[i] = xnh[i]; xfl[i] = xnl[i]; }
        }
    }
#undef LOADX
#undef ISSUEQ
#undef PROCQ
}

extern "C" void kernel_launch(void* const* d_in, const int* in_sizes, int n_in,
                              void* d_out, int out_size, void* d_ws, size_t ws_size,
                              hipStream_t stream) {
    const int want[6] = {33554432, 16384, 393216, 786432, 1536, 1536};
    const void* res[6] = {nullptr, nullptr, nullptr, nullptr, nullptr, nullptr};
    bool used[64] = {false};
    for (int k = 0; k < 6; ++k)
        for (int i = 0; i < n_in && i < 64; ++i)
            if (!used[i] && in_sizes[i] == want[k]) { res[k] = d_in[i]; used[i] = true; break; }
    bool ok = true;
    for (int k = 0; k < 6; ++k) if (!res[k]) ok = false;
    if (!ok) for (int k = 0; k < 6; ++k) res[k] = d_in[k];

    const float* x       = (const float*)res[0];
    const void*  is_init = res[1];
    const float* w_ih    = (const float*)res[2];
    const float* w_hh    = (const float*)res[3];
    const float* b_ih    = (const float*)res[4];
    const float* b_hh    = (const float*)res[5];
    float* out = (float*)d_out;

    gru_prep<<<1, 256, 0, stream>>>((const unsigned int*)is_init);

    hipFuncSetAttribute((const void*)gru_main,
                        hipFuncAttributeMaxDynamicSharedMemorySize, kSmem);
    gru_main<<<256, 256, kSmem, stream>>>(x, is_init, w_ih, w_hh, b_ih, b_hh, out);
}

// Round 19
// 3806.636 us; speedup vs baseline: 1.4728x; 1.4728x over previous
//
#include <hip/hip_runtime.h>
#include <hip/hip_bf16.h>

typedef __attribute__((ext_vector_type(8))) _Float16 half8;
typedef __attribute__((ext_vector_type(4))) float f32x4;
typedef __attribute__((ext_vector_type(4))) unsigned int uint4v;
typedef __attribute__((ext_vector_type(4))) int int32x4;

// CK-style raw buffer load (compiler-tracked vmcnt, explicit cache policy).
// aux=3 -> sc0|sc1: bypass L1+L2, served at the L3 coherence point.
__device__ int32x4 buf_ld_x4(int32x4 rsrc, unsigned voffset, unsigned soffset,
                             unsigned aux) __asm("llvm.amdgcn.raw.buffer.load.v4i32");

#define MFMA_F16(a,b,c) __builtin_amdgcn_mfma_f32_16x16x32_f16((a),(b),(c),0,0,0)

namespace {
constexpr int kNS = 256, kNA = 8, kNI = 256, kNH = 512;
constexpr size_t kOutElems = (size_t)64*kNS*kNA*kNH;  // 33,554,432
constexpr float kScale = 2048.0f;
constexpr float kInv   = 1.0f/2048.0f;
constexpr int kWihHi = 0;
constexpr int kWihLo = 24576;
constexpr int kWhhHi = 49152;
constexpr int kWhhLo = 98304;
constexpr int kSmem  = 147456;     // 147 KB dynamic -> 1 wg/CU
constexpr size_t kHPhase = 262144; // u32 elements per phase (512x512)
}

// h exchange: packed u32 (fp16 hi | lo<<16), layout (R18-validated):
// idx = (mi*4+w)*8192 + kb*512 + l*8 + e  -> lane l reads TWO dwordx4 per kb.
// Reads: buffer_load_dwordx4 sc0 sc1 (L3). Writes: agent-scope atomic dwords
// (write-through; L3-visible). Sync: per-wg step-stamped flags.
__device__ unsigned int g_hpk[2*kHPhase];   // 2 MB
__device__ unsigned int g_flag[4096];       // 256 wgs x 16-dword stride
__device__ int          g_mode;             // is_init dtype

__device__ __forceinline__ float sigmoid_f(float v) { return 1.0f/(1.0f + __expf(-v)); }
__device__ __forceinline__ float tanh_f(float v) {
    float e = __expf(2.0f*v);
    return 1.0f - 2.0f/(e + 1.0f);
}
__device__ __forceinline__ void split2(float v, unsigned short& hi, unsigned short& lo) {
    _Float16 h = (_Float16)v;
    _Float16 l = (_Float16)((v - (float)h) * kScale);
    hi = __builtin_bit_cast(unsigned short, h);
    lo = __builtin_bit_cast(unsigned short, l);
}

__global__ void gru_prep(const unsigned int* __restrict__ is_init_raw) {
    for (int i = threadIdx.x; i < 4096; i += 256)
        __hip_atomic_store(&g_flag[i], 0u, __ATOMIC_RELAXED, __HIP_MEMORY_SCOPE_AGENT);
    if (threadIdx.x == 0) g_mode = 0;
    __syncthreads();
    unsigned m = 0;
    for (int i = threadIdx.x; i < 4096; i += 256) {
        unsigned v = is_init_raw[i];
        if (v == 0x00003F80u || v == 0x3F803F80u) m |= 4u;
        else if (v == 0x3F800000u)                m |= 2u;
        else if (v > 1u)                          m |= 1u;
    }
    if (m) atomicOr(&g_mode, (int)m);
}

// Persistent GRU. 256 wgs x 256 thr; 1 wg/CU. mi = bx&7 (8 groups x 64 rows,
// 32 wgs/group), ci = bx>>3 (32 col-blocks x 16). Split-fp16 MFMA, fp32 h.
__global__ void __launch_bounds__(256, 1)
gru_main(const float* __restrict__ x, const void* __restrict__ is_init,
         const float* __restrict__ w_ih, const float* __restrict__ w_hh,
         const float* __restrict__ b_ih, const float* __restrict__ b_hh,
         float* __restrict__ out)
{
    extern __shared__ char smem[];
    const int tid = threadIdx.x;
    const int bx  = blockIdx.x;
    const int mi  = bx & 7;
    const int ci  = bx >> 3;
    const int c0  = ci * 16;

    for (int idx = tid; idx < 3072; idx += 256) {           // w_ih: 48 x 64 float4
        int jr = idx >> 6, q = idx & 63;
        int j = (jr >> 4)*kNH + c0 + (jr & 15);
        float4 v = *(const float4*)(w_ih + (size_t)j*kNI + q*4);
        ushort4 hi, lo;
        split2(v.x, hi.x, lo.x); split2(v.y, hi.y, lo.y);
        split2(v.z, hi.z, lo.z); split2(v.w, hi.w, lo.w);
        unsigned off = ((unsigned)(jr*512 + q*8)) ^ ((unsigned)(jr & 7) << 4);
        *(ushort4*)(smem + kWihHi + off) = hi;
        *(ushort4*)(smem + kWihLo + off) = lo;
    }
    for (int idx = tid; idx < 6144; idx += 256) {           // w_hh: 48 x 128 float4
        int jr = idx >> 7, q = idx & 127;
        int j = (jr >> 4)*kNH + c0 + (jr & 15);
        float4 v = *(const float4*)(w_hh + (size_t)j*kNH + q*4);
        ushort4 hi, lo;
        split2(v.x, hi.x, lo.x); split2(v.y, hi.y, lo.y);
        split2(v.z, hi.z, lo.z); split2(v.w, hi.w, lo.w);
        unsigned off = ((unsigned)(jr*1024 + q*8)) ^ ((unsigned)(jr & 7) << 4);
        *(ushort4*)(smem + kWhhHi + off) = hi;
        *(ushort4*)(smem + kWhhLo + off) = lo;
    }
    __syncthreads();

    const int fm = g_mode;
    const int fmode = (fm & 4) ? 3 : (fm & 2) ? 2 : (fm & 1) ? 1 : 0;

    const int l    = tid & 63, w = tid >> 6;
    const int lrow = l & 15, kgrp = l >> 4;

    const int cE = c0 + lrow;
    const int mA = mi*64 + w*16 + lrow;
    const int bA = mA >> 3;
    const size_t xrow0 = ((size_t)bA*(kNS*kNA) + (mA & 7))*kNI + kgrp*8;

    const unsigned swzb = (unsigned)(lrow & 7) << 4;
    unsigned wihB[3], whhB[3];
    #pragma unroll
    for (int g = 0; g < 3; ++g) {
        wihB[g] = (unsigned)((g*16 + lrow)*512  + kgrp*16);
        whhB[g] = (unsigned)((g*16 + lrow)*1024 + kgrp*16);
    }

    const float biasR  = b_ih[cE]        + b_hh[cE];
    const float biasZ  = b_ih[kNH + cE]  + b_hh[kNH + cE];
    const float biasIN = b_ih[2*kNH + cE];
    const float biasHN = b_hh[2*kNH + cE];
    const int mE0 = mi*64 + w*16 + kgrp*4;
    const int bE  = mE0 >> 3, aE0 = mE0 & 7;

    float hreg[4] = {0.f, 0.f, 0.f, 0.f};
    float* hn_out = out + kOutElems;
    int dead = 0;
    const unsigned myFlag  = (unsigned)((mi*32 + ci)*16);
    const unsigned grpFlag = (unsigned)(mi*32)*16;

    // Exchange addressing (R18-validated layout), element units
    const unsigned hRdBase = (unsigned)((mi*4 + w)*8192);   // + kb*512 + l*8 + e
    const unsigned hWrBase = (unsigned)((mi*4 + w)*8192
                              + ((cE >> 5) * 512)
                              + ((((cE >> 3) & 3)*16 + kgrp*4) * 8)
                              + (cE & 7));                  // + i*8

    // SRD over g_hpk (bounds disabled, raw dword access)
    int32x4 srd;
    {
        unsigned long long base = (unsigned long long)(const void*)g_hpk;
        srd[0] = (int)(base & 0xFFFFFFFFull);
        srd[1] = (int)(base >> 32);
        srd[2] = (int)0xFFFFFFFFu;
        srd[3] = 0x00020000;
    }
    const unsigned rdByte = (hRdBase + (unsigned)l*8u)*4u;  // + phase + kb*2048

#define LOADX(dh, dl, ss) do {                                                     \
        const float* xr_ = x + xrow0 + (size_t)(ss)*(kNA*kNI);                     \
        _Pragma("unroll")                                                          \
        for (int kb_ = 0; kb_ < 8; ++kb_) {                                        \
            float4 v0_ = *(const float4*)(xr_ + kb_*32);                           \
            float4 v1_ = *(const float4*)(xr_ + kb_*32 + 4);                       \
            float vv_[8] = {v0_.x,v0_.y,v0_.z,v0_.w,v1_.x,v1_.y,v1_.z,v1_.w};      \
            half8 th_, tl_;                                                        \
            _Pragma("unroll")                                                      \
            for (int e_ = 0; e_ < 8; ++e_) {                                       \
                _Float16 h_ = (_Float16)vv_[e_];                                   \
                th_[e_] = h_;                                                      \
                tl_[e_] = (_Float16)((vv_[e_] - (float)h_) * kScale);              \
            }                                                                      \
            dh[kb_] = th_; dl[kb_] = tl_;                                          \
        }                                                                          \
    } while (0)

    half8 xfh[8], xfl[8], xnh[8], xnl[8];
    LOADX(xfh, xfl, 0);
    #pragma unroll
    for (int i = 0; i < 8; ++i) { xnh[i] = xfh[i]; xnl[i] = xfl[i]; }

    for (int s = 0; s < kNS; ++s) {
        const int ii = bA*kNS + s;
        const int ie = bE*kNS + s;
        int iniA, iniE;
        switch (fmode) {
            case 3:  iniA = ((const unsigned short*)is_init)[ii] != 0;
                     iniE = ((const unsigned short*)is_init)[ie] != 0; break;
            case 2:  iniA = ((const float*)is_init)[ii] != 0.f;
                     iniE = ((const float*)is_init)[ie] != 0.f;       break;
            case 1:  iniA = ((const unsigned char*)is_init)[ii] != 0;
                     iniE = ((const unsigned char*)is_init)[ie] != 0; break;
            default: iniA = ((const int*)is_init)[ii] != 0;
                     iniE = ((const int*)is_init)[ie] != 0;           break;
        }
        f32x4 aR = {0,0,0,0}, aZ = {0,0,0,0}, aGN = {0,0,0,0}, aHN = {0,0,0,0};
        f32x4 lR = {0,0,0,0}, lZ = {0,0,0,0}, lGN = {0,0,0,0}, lHN = {0,0,0,0};

        // ---- gi (x from regs, weights from LDS; independent of h) ----
        #pragma unroll
        for (int kb = 0; kb < 8; ++kb) {
            {   half8 bhi = *(const half8*)(smem + kWihHi + ((wihB[0] + kb*64) ^ swzb));
                half8 blo = *(const half8*)(smem + kWihLo + ((wihB[0] + kb*64) ^ swzb));
                aR = MFMA_F16(xfh[kb], bhi, aR);
                lR = MFMA_F16(xfl[kb], bhi, lR);
                lR = MFMA_F16(xfh[kb], blo, lR); }
            {   half8 bhi = *(const half8*)(smem + kWihHi + ((wihB[1] + kb*64) ^ swzb));
                half8 blo = *(const half8*)(smem + kWihLo + ((wihB[1] + kb*64) ^ swzb));
                aZ = MFMA_F16(xfh[kb], bhi, aZ);
                lZ = MFMA_F16(xfl[kb], bhi, lZ);
                lZ = MFMA_F16(xfh[kb], blo, lZ); }
            {   half8 bhi = *(const half8*)(smem + kWihHi + ((wihB[2] + kb*64) ^ swzb));
                half8 blo = *(const half8*)(smem + kWihLo + ((wihB[2] + kb*64) ^ swzb));
                aGN = MFMA_F16(xfh[kb], bhi, aGN);
                lGN = MFMA_F16(xfl[kb], bhi, lGN);
                lGN = MFMA_F16(xfh[kb], blo, lGN); }
        }

        // ---- wait for h(s): 32 lanes poll 32 producer flags in parallel ----
        if (s > 0) {
            if (tid < 32 && !dead) {
                const unsigned target = (unsigned)s;
                long it = 0;
                while (__hip_atomic_load(&g_flag[grpFlag + tid*16], __ATOMIC_RELAXED,
                                         __HIP_MEMORY_SCOPE_AGENT) < target) {
                    if (++it > 50000000L) { dead = 1; break; }
                    __builtin_amdgcn_s_sleep(1);
                }
            }
            __syncthreads();
            // gh: 2 x dwordx4 (sc0 sc1) per kb; compiler schedules/pipes waits
            const unsigned vb = ((s & 1) ? (unsigned)(kHPhase*4) : 0u) + rdByte;
            const half8 zz = {};
            #pragma unroll
            for (int kb = 0; kb < 16; ++kb) {
                int32x4 q0i = buf_ld_x4(srd, vb + (unsigned)kb*2048u,      0u, 3u);
                int32x4 q1i = buf_ld_x4(srd, vb + (unsigned)kb*2048u + 16u, 0u, 3u);
                uint4v q0 = __builtin_bit_cast(uint4v, q0i);
                uint4v q1 = __builtin_bit_cast(uint4v, q1i);
                uint4v ph, pl;
                ph[0]=(q0[0]&0xFFFFu)|(q0[1]<<16); pl[0]=(q0[0]>>16)|(q0[1]&0xFFFF0000u);
                ph[1]=(q0[2]&0xFFFFu)|(q0[3]<<16); pl[1]=(q0[2]>>16)|(q0[3]&0xFFFF0000u);
                ph[2]=(q1[0]&0xFFFFu)|(q1[1]<<16); pl[2]=(q1[0]>>16)|(q1[1]&0xFFFF0000u);
                ph[3]=(q1[2]&0xFFFFu)|(q1[3]<<16); pl[3]=(q1[2]>>16)|(q1[3]&0xFFFF0000u);
                half8 ahi = __builtin_bit_cast(half8, ph);
                half8 alo = __builtin_bit_cast(half8, pl);
                ahi = iniA ? zz : ahi;
                alo = iniA ? zz : alo;
                {   half8 bhi = *(const half8*)(smem + kWhhHi + ((whhB[0] + kb*64) ^ swzb));
                    half8 blo = *(const half8*)(smem + kWhhLo + ((whhB[0] + kb*64) ^ swzb));
                    aR = MFMA_F16(ahi, bhi, aR);
                    lR = MFMA_F16(alo, bhi, lR);
                    lR = MFMA_F16(ahi, blo, lR); }
                {   half8 bhi = *(const half8*)(smem + kWhhHi + ((whhB[1] + kb*64) ^ swzb));
                    half8 blo = *(const half8*)(smem + kWhhLo + ((whhB[1] + kb*64) ^ swzb));
                    aZ = MFMA_F16(ahi, bhi, aZ);
                    lZ = MFMA_F16(alo, bhi, lZ);
                    lZ = MFMA_F16(ahi, blo, lZ); }
                {   half8 bhi = *(const half8*)(smem + kWhhHi + ((whhB[2] + kb*64) ^ swzb));
                    half8 blo = *(const half8*)(smem + kWhhLo + ((whhB[2] + kb*64) ^ swzb));
                    aHN = MFMA_F16(ahi, bhi, aHN);
                    lHN = MFMA_F16(alo, bhi, lHN);
                    lHN = MFMA_F16(ahi, blo, lHN); }
            }
        }

        // ---- gates + h update; h stores (write-through atomics) first ----
        unsigned int* hw = g_hpk + (size_t)((s+1) & 1)*kHPhase + hWrBase;
        float hvout[4];
        #pragma unroll
        for (int i = 0; i < 4; ++i) {
            float pr  = aR[i]  + lR[i]*kInv  + biasR;
            float pz  = aZ[i]  + lZ[i]*kInv  + biasZ;
            float gin = aGN[i] + lGN[i]*kInv + biasIN;
            float ghn = aHN[i] + lHN[i]*kInv + biasHN;
            float htv = iniE ? 0.f : hreg[i];
            float r  = sigmoid_f(pr);
            float zg = sigmoid_f(pz);
            float nn = tanh_f(gin + r*ghn);
            float hv = (1.f - zg)*nn + zg*htv;
            hreg[i] = hv; hvout[i] = hv;
            unsigned short shi, slo;
            split2(hv, shi, slo);
            unsigned int pk = (unsigned)shi | ((unsigned)slo << 16);
            __hip_atomic_store(&hw[i*8], pk, __ATOMIC_RELAXED, __HIP_MEMORY_SCOPE_AGENT);
        }

        // ---- publish h(s+1): barrier drains ONLY the h stores (x(s+1) not
        //      yet issued -> HBM x latency stays off the critical path) ----
        if (s < kNS-1) {
            __syncthreads();
            if (tid == 0)
                __hip_atomic_store(&g_flag[myFlag], (unsigned)(s+1),
                                   __ATOMIC_RELAXED, __HIP_MEMORY_SCOPE_AGENT);
        }

        // ---- off the critical path: x prefetch for s+1, then out stores ----
        if (s + 1 < kNS) LOADX(xnh, xnl, s + 1);

        const size_t obase = ((size_t)bE*(kNS*kNA) + (size_t)s*kNA + aE0)*kNH + cE;
        #pragma unroll
        for (int i = 0; i < 4; ++i)
            out[obase + (size_t)i*kNH] = hvout[i];
        if (s == kNS-1) {
            #pragma unroll
            for (int i = 0; i < 4; ++i)
                hn_out[(size_t)(mE0 + i)*kNH + cE] = hreg[i];
        }

        if (s < kNS-1) {
            #pragma unroll
            for (int i = 0; i < 8; ++i) { xfh[i] = xnh[i]; xfl[i] = xnl[i]; }
        }
    }
#undef LOADX
}

extern "C" void kernel_launch(void* const* d_in, const int* in_sizes, int n_in,
                              void* d_out, int out_size, void* d_ws, size_t ws_size,
                              hipStream_t stream) {
    const int want[6] = {33554432, 16384, 393216, 786432, 1536, 1536};
    const void* res[6] = {nullptr, nullptr, nullptr, nullptr, nullptr, nullptr};
    bool used[64] = {false};
    for (int k = 0; k < 6; ++k)
        for (int i = 0; i < n_in && i < 64; ++i)
            if (!used[i] && in_sizes[i] == want[k]) { res[k] = d_in[i]; used[i] = true; break; }
    bool ok = true;
    for (int k = 0; k < 6; ++k) if (!res[k]) ok = false;
    if (!ok) for (int k = 0; k < 6; ++k) res[k] = d_in[k];

    const float* x       = (const float*)res[0];
    const void*  is_init = res[1];
    const float* w_ih    = (const float*)res[2];
    const float* w_hh    = (const float*)res[3];
    const float* b_ih    = (const float*)res[4];
    const float* b_hh    = (const float*)res[5];
    float* out = (float*)d_out;

    gru_prep<<<1, 256, 0, stream>>>((const unsigned int*)is_init);

    hipFuncSetAttribute((const void*)gru_main,
                        hipFuncAttributeMaxDynamicSharedMemorySize, kSmem);
    gru_main<<<256, 256, kSmem, stream>>>(x, is_init, w_ih, w_hh, b_ih, b_hh, out);
}